// Round 3
// baseline (6274.854 us; speedup 1.0000x reference)
//
#include <hip/hip_runtime.h>

typedef unsigned short u16;
typedef __attribute__((ext_vector_type(4))) float f32x4;
typedef __attribute__((ext_vector_type(8))) short short8;

#define B_ 64
#define L_ 196
#define D_ 512
#define T_ 31
#define V_ 32000

__device__ __forceinline__ float b2f(unsigned int u) {
    union { float f; unsigned int u; } x; x.u = u << 16; return x.f;
}
__device__ __forceinline__ u16 f2b(float f) {
    union { float f; unsigned int u; } x; x.f = f;
    unsigned int r = x.u + 0x7fffu + ((x.u >> 16) & 1u);
    return (u16)(r >> 16);
}
__device__ __forceinline__ void unpack8(uint4 v, float* f) {
    f[0] = b2f(v.x & 0xffffu); f[1] = b2f(v.x >> 16);
    f[2] = b2f(v.y & 0xffffu); f[3] = b2f(v.y >> 16);
    f[4] = b2f(v.z & 0xffffu); f[5] = b2f(v.z >> 16);
    f[6] = b2f(v.w & 0xffffu); f[7] = b2f(v.w >> 16);
}
// 8 bf16 (uint4) * 8 f32 -> acc
__device__ __forceinline__ void fma8(uint4 q, const float* x, float& acc) {
    acc += b2f(q.x & 0xffffu) * x[0]; acc += b2f(q.x >> 16) * x[1];
    acc += b2f(q.y & 0xffffu) * x[2]; acc += b2f(q.y >> 16) * x[3];
    acc += b2f(q.z & 0xffffu) * x[4]; acc += b2f(q.z >> 16) * x[5];
    acc += b2f(q.w & 0xffffu) * x[6]; acc += b2f(q.w >> 16) * x[7];
}

// ------------- bulk f32 -> bf16 convert, 4 elems/thread ----------------------
__global__ __launch_bounds__(256) void convert_kernel(
        const float* __restrict__ src, u16* __restrict__ dst, int n4) {
    int i = blockIdx.x * 256 + threadIdx.x;
    if (i >= n4) return;
    float4 v = *(const float4*)(src + (size_t)i * 4);
    u16* d = dst + (size_t)i * 4;
    d[0] = f2b(v.x); d[1] = f2b(v.y); d[2] = f2b(v.z); d[3] = f2b(v.w);
}

// ------------- prep: WfT, Wcat = [W_ih[:,512:] ; W_hh], Wemb, emb, bsum ------
__global__ __launch_bounds__(256) void prep_kernel(
        const float* __restrict__ Wfeat, const float* __restrict__ Wih,
        const float* __restrict__ Whh, const float* __restrict__ table,
        const int* __restrict__ cap, const float* __restrict__ bih,
        const float* __restrict__ bhh,
        u16* __restrict__ WfT, u16* __restrict__ Wcat,
        u16* __restrict__ Wemb, u16* __restrict__ Aemb,
        float* __restrict__ bsum) {
    int idx = blockIdx.x * 256 + threadIdx.x;
    if (idx < 2048) bsum[idx] = bih[idx] + bhh[idx];
    if (idx < 512 * 512) {
        WfT[idx] = f2b(Wfeat[(idx & 511) * 512 + (idx >> 9)]);
    }
    if (idx < 2048 * 1024) {
        int j = idx >> 10, k = idx & 1023;
        Wcat[idx] = f2b((k < 512) ? Wih[j * 1024 + 512 + k] : Whh[j * 512 + (k - 512)]);
    }
    if (idx < 2048 * 512) {
        int j = idx >> 9, k = idx & 511;
        Wemb[idx] = f2b(Wih[j * 1024 + k]);
    }
    if (idx < 1984 * 512) {
        int m = idx >> 9, k = idx & 511;       // m = t*64 + b
        int t = m >> 6, b = m & 63;
        Aemb[idx] = f2b(table[(size_t)cap[b * 32 + t] * 512 + k]);
    }
}

// ------------- persistent per-batch kernel: whole 31-step recurrence ---------
// 64 blocks (one per batch) x 512 threads. NO inter-block sync needed: the
// recurrence is fully batch-independent. All state (h, c, hWh, context) lives
// in LDS/registers across all 31 steps; per-step global writes are just
// hseq (1 KB bf16) + alphas (784 B).
__global__ __launch_bounds__(512) void loop_kernel(
        const float* __restrict__ img,   // [64,196,512] f32
        const u16*   __restrict__ fpb,   // [12544,512] bf16 feat_proj
        const float* __restrict__ Wh,    // [512,512] f32
        const float* __restrict__ ab,    // [196]
        const float* __restrict__ va,    // [512]
        const u16*   __restrict__ Wcat,  // [2048,1024] bf16 rows: i,f,g,o
        const float* __restrict__ gemb,  // [1984,2048] f32 (biases folded in)
        u16*   __restrict__ hseq,        // [1984,512] bf16, row m = b*31+t
        float* __restrict__ alph) {      // [64,31,196]
    __shared__ __align__(16) float xf[1024];     // [context(512) | h(512)] f32
    __shared__ __align__(16) float hl[512];      // h f32 (for hWh)
    __shared__ __align__(16) float hWh_l[512];   // h @ W_h
    __shared__ float score_l[196];
    __shared__ float al[196];
    __shared__ float abl[196];
    __shared__ float sl[256];

    int b = blockIdx.x;
    int tid = threadIdx.x;
    int lane = tid & 63;
    int wv = tid >> 6;
    int d = tid;                                  // 0..511

    // ---- prologue: abl, va regs, h0 = c0 = mean_l(img), hWh(0) -------------
    if (tid < 196) abl[tid] = ab[tid];
    float4 v0 = *(const float4*)(va + lane * 8);
    float4 v1 = *(const float4*)(va + lane * 8 + 4);
    float vv[8] = {v0.x, v0.y, v0.z, v0.w, v1.x, v1.y, v1.z, v1.w};

    {
        const float* p = img + (size_t)b * L_ * D_ + d;
        float s = 0.f;
        for (int l = 0; l < L_; l++) s += p[l * D_];
        float mean = s * (1.0f / 196.0f);
        hl[d] = mean;
        xf[512 + d] = mean;
        // c in register, owned by thread d for the whole loop
        float c_reg = mean;
        __syncthreads();
        float acc = 0.f;
        const float* wp = Wh + d;
        for (int k = 0; k < 512; k++) acc += hl[k] * wp[(size_t)k * 512];
        hWh_l[d] = acc;
        __syncthreads();

        for (int t = 0; t < T_; t++) {
            // ---------------- score: wave per l, 8 waves --------------------
            {
                float hh[8];
                *(float4*)hh = *(const float4*)(&hWh_l[lane * 8]);
                *(float4*)(hh + 4) = *(const float4*)(&hWh_l[lane * 8 + 4]);
                for (int l = wv; l < L_; l += 8) {
                    uint4 fv = *(const uint4*)(fpb + ((size_t)(b * L_ + l)) * D_ + lane * 8);
                    float f[8];
                    unpack8(fv, f);
                    float abv = abl[l];
                    float acc2 = 0.f;
#pragma unroll
                    for (int j = 0; j < 8; j++) {
                        float a = f[j] + hh[j] + abv;
                        a = fmaxf(a, 0.f);
                        acc2 += a * vv[j];
                    }
#pragma unroll
                    for (int off = 32; off; off >>= 1) acc2 += __shfl_xor(acc2, off, 64);
                    if (lane == 0) score_l[l] = acc2;
                }
            }
            __syncthreads();
            // ---------------- softmax over 196 ------------------------------
            if (tid < 256) sl[tid] = (tid < L_) ? score_l[tid] : -3.4e38f;
            __syncthreads();
            for (int off = 128; off; off >>= 1) {
                if (tid < off) sl[tid] = fmaxf(sl[tid], sl[tid + off]);
                __syncthreads();
            }
            float mx = sl[0];
            __syncthreads();
            float e = (tid < L_) ? expf(score_l[tid] - mx) : 0.f;
            if (tid < L_) al[tid] = e;
            if (tid < 256) sl[tid] = e;
            __syncthreads();
            for (int off = 128; off; off >>= 1) {
                if (tid < off) sl[tid] += sl[tid + off];
                __syncthreads();
            }
            float inv = 1.f / sl[0];
            if (tid < L_) {
                float a = al[tid] * inv;
                al[tid] = a;
                alph[((size_t)(b * T_ + t)) * L_ + tid] = a;
            }
            __syncthreads();
            // ---------------- context: xf[d] = sum_l al[l]*img[b,l,d] -------
            {
                float cacc = 0.f;
                const float* ib = img + (size_t)b * L_ * D_ + d;
#pragma unroll 4
                for (int l = 0; l < L_; l++) cacc += al[l] * ib[(size_t)l * D_];
                xf[d] = cacc;
            }
            __syncthreads();
            // ---------------- gates GEMV: thread d -> rows d,512+d,1024+d,1536+d
            float gi, gf, gg, go;
            {
                const u16* w0 = Wcat + (size_t)d * 1024;
                const u16* w1 = w0 + 512 * 1024;
                const u16* w2 = w0 + 1024 * 1024;
                const u16* w3 = w0 + 1536 * 1024;
                float a0 = 0.f, a1 = 0.f, a2 = 0.f, a3 = 0.f;
#pragma unroll 2
                for (int k = 0; k < 1024; k += 8) {
                    float xk[8];
                    *(float4*)xk = *(const float4*)(&xf[k]);
                    *(float4*)(xk + 4) = *(const float4*)(&xf[k + 4]);
                    uint4 q0 = *(const uint4*)(w0 + k);
                    uint4 q1 = *(const uint4*)(w1 + k);
                    uint4 q2 = *(const uint4*)(w2 + k);
                    uint4 q3 = *(const uint4*)(w3 + k);
                    fma8(q0, xk, a0);
                    fma8(q1, xk, a1);
                    fma8(q2, xk, a2);
                    fma8(q3, xk, a3);
                }
                const float* ge = gemb + ((size_t)(t * 64 + b)) * 2048;
                gi = a0 + ge[d];
                gf = a1 + ge[512 + d];
                gg = a2 + ge[1024 + d];
                go = a3 + ge[1536 + d];
            }
            // RACE FIX: all threads must finish reading xf[512..1023] (h(t-1))
            // in the GEMV above before any thread overwrites xf[512+d] = h(t).
            __syncthreads();
            // ---------------- LSTM pointwise (all in registers) -------------
            {
                float si = 1.f / (1.f + expf(-gi));
                float sf = 1.f / (1.f + expf(-gf));
                float so = 1.f / (1.f + expf(-go));
                float cn = sf * c_reg + si * tanhf(gg);
                c_reg = cn;
                float hn = so * tanhf(cn);
                hseq[((size_t)(b * T_ + t)) * 512 + d] = f2b(hn);
                hl[d] = hn;
                xf[512 + d] = hn;
            }
            __syncthreads();
            // ---------------- hWh for next step -----------------------------
            {
                float acc = 0.f;
                const float* wp = Wh + d;
#pragma unroll 4
                for (int k = 0; k < 512; k++) acc += hl[k] * wp[(size_t)k * 512];
                hWh_l[d] = acc;
            }
            __syncthreads();
        }
    }
}

// ------------- generic MFMA GEMM: C[MxN] = A[MxK] @ B_T[NxK]^T ---------------
// 64x64 block tile, 4 waves 2x2, each wave 2x2 MFMA tiles of 16x16, BK=32
// MODE 0: C(bf16) = bf16(acc)       MODE 1: C(f32) = acc + bias[n] (NT store)
// MODE 2: C(f32) = acc              MODE 3: C(f32) = acc + bias[n]
// SWZ 1: XCD-bijective remap for the final 15500-block (500x31) GEMM:
//        each XCD owns a contiguous N-chunk, M iterates fastest -> B panel
//        (64x512 bf16 = 65 KB) stays in that XCD's L2 across all 31 M-tiles.
template <int MODE, int SWZ>
__global__ __launch_bounds__(256) void gemm64_kernel(
        const u16* __restrict__ A, const u16* __restrict__ Bm,
        int lda, int ldb, int K, void* __restrict__ Cv, int ldc,
        const float* __restrict__ bias) {
    __shared__ __align__(16) u16 At[64 * 40];
    __shared__ __align__(16) u16 Bt[64 * 40];
    int tid = threadIdx.x, wave = tid >> 6, lane = tid & 63;
    int wm = (wave >> 1) * 32, wn = (wave & 1) * 32;
    size_t m0, n0;
    if (SWZ) {
        unsigned lin = blockIdx.y * gridDim.x + blockIdx.x;   // dispatch order
        const unsigned q = 15500u / 8u, r = 15500u % 8u;      // 1937, 4
        unsigned xcd = lin & 7u, pos = lin >> 3;
        unsigned wg = (xcd < r ? xcd * (q + 1u) : r * (q + 1u) + (xcd - r) * q) + pos;
        unsigned mt = wg % 31u, nt = wg / 31u;
        m0 = (size_t)mt * 64; n0 = (size_t)nt * 64;
    } else {
        m0 = (size_t)blockIdx.y * 64; n0 = (size_t)blockIdx.x * 64;
    }
    f32x4 acc[2][2];
#pragma unroll
    for (int i = 0; i < 2; i++)
#pragma unroll
        for (int j = 0; j < 2; j++) acc[i][j] = {0.f, 0.f, 0.f, 0.f};
    int sr = tid >> 2, sc = (tid & 3) * 8;
    const u16* Ap = A + (m0 + sr) * (size_t)lda + sc;
    const u16* Bp = Bm + (n0 + sr) * (size_t)ldb + sc;
    int fm = lane & 15, fk = (lane >> 4) * 8;
    for (int k0 = 0; k0 < K; k0 += 32) {
        uint4 av = *(const uint4*)(Ap + k0);
        uint4 bv = *(const uint4*)(Bp + k0);
        __syncthreads();
        *(uint4*)(&At[sr * 40 + sc]) = av;
        *(uint4*)(&Bt[sr * 40 + sc]) = bv;
        __syncthreads();
        short8 a0 = *(const short8*)(&At[(wm + fm) * 40 + fk]);
        short8 a1 = *(const short8*)(&At[(wm + 16 + fm) * 40 + fk]);
        short8 b0 = *(const short8*)(&Bt[(wn + fm) * 40 + fk]);
        short8 b1 = *(const short8*)(&Bt[(wn + 16 + fm) * 40 + fk]);
        acc[0][0] = __builtin_amdgcn_mfma_f32_16x16x32_bf16(a0, b0, acc[0][0], 0, 0, 0);
        acc[0][1] = __builtin_amdgcn_mfma_f32_16x16x32_bf16(a0, b1, acc[0][1], 0, 0, 0);
        acc[1][0] = __builtin_amdgcn_mfma_f32_16x16x32_bf16(a1, b0, acc[1][0], 0, 0, 0);
        acc[1][1] = __builtin_amdgcn_mfma_f32_16x16x32_bf16(a1, b1, acc[1][1], 0, 0, 0);
    }
    int crow = (lane >> 4) * 4, ccol = lane & 15;
#pragma unroll
    for (int mi = 0; mi < 2; mi++)
#pragma unroll
        for (int ni = 0; ni < 2; ni++)
#pragma unroll
            for (int r = 0; r < 4; r++) {
                size_t row = m0 + wm + mi * 16 + crow + r;
                size_t col = n0 + wn + ni * 16 + ccol;
                float v = acc[mi][ni][r];
                if (MODE == 0) {
                    ((u16*)Cv)[row * (size_t)ldc + col] = f2b(v);
                } else if (MODE == 1) {
                    v += bias[col];
                    __builtin_nontemporal_store(v, (float*)Cv + row * (size_t)ldc + col);
                } else {
                    if (MODE == 3) v += bias[col];
                    ((float*)Cv)[row * (size_t)ldc + col] = v;
                }
            }
}

extern "C" void kernel_launch(void* const* d_in, const int* in_sizes, int n_in,
                              void* d_out, int out_size, void* d_ws, size_t ws_size,
                              hipStream_t stream) {
    (void)in_sizes; (void)n_in; (void)out_size; (void)ws_size;
    const float* img   = (const float*)d_in[0];
    const int*   cap   = (const int*)d_in[1];
    const float* table = (const float*)d_in[2];
    const float* Wf    = (const float*)d_in[3];
    const float* Wh    = (const float*)d_in[4];
    const float* ab    = (const float*)d_in[5];
    const float* va    = (const float*)d_in[6];
    const float* Wih   = (const float*)d_in[7];
    const float* Whh   = (const float*)d_in[8];
    const float* bih   = (const float*)d_in[9];
    const float* bhh   = (const float*)d_in[10];
    const float* Wout  = (const float*)d_in[11];
    const float* bout  = (const float*)d_in[12];

    float* dout = (float*)d_out;                    // predictions [64,31,32000]
    float* alph = dout + (size_t)B_ * T_ * V_;      // alphas [64,31,196]

    char* w = (char*)d_ws;
    u16*   imgb  = (u16*)(w);                       // [12544,512] bf16
    u16*   fpb   = (u16*)(w + 12845056);            // [12544,512] bf16
    u16*   Woutb = (u16*)(w + 25690112);            // [32000,512] bf16
    u16*   Wcat  = (u16*)(w + 58458112);            // [2048,1024] bf16
    u16*   Wemb  = (u16*)(w + 62652416);            // [2048,512]  bf16
    u16*   WfT   = (u16*)(w + 64749568);            // [512,512]   bf16
    u16*   Aemb  = (u16*)(w + 65273856);            // [1984,512]  bf16
    u16*   hseq  = (u16*)(w + 67305472);            // [1984,512]  bf16
    float* gemb  = (float*)(w + 69337088);          // [1984,2048] f32
    float* bsum  = (float*)(w + 85590016);          // [2048]      f32

    // upfront conversions / packing
    convert_kernel<<<6272, 256, 0, stream>>>(img, imgb, 12544 * 512 / 4);
    convert_kernel<<<16000, 256, 0, stream>>>(Wout, Woutb, 32000 * 512 / 4);
    prep_kernel<<<8192, 256, 0, stream>>>(Wf, Wih, Whh, table, cap, bih, bhh,
                                          WfT, Wcat, Wemb, Aemb, bsum);
    // feat_proj = img @ W_feat : [12544,512] -> bf16
    gemm64_kernel<0, 0><<<dim3(8, 196), 256, 0, stream>>>(imgb, WfT, 512, 512, 512, fpb, 512, nullptr);
    // gates_emb = emb @ W_ih[:, :512].T + (bih+bhh) : [1984,2048] -> f32
    gemm64_kernel<3, 0><<<dim3(32, 31), 256, 0, stream>>>(Aemb, Wemb, 512, 512, 512, gemb, 2048, bsum);

    // whole 31-step recurrence: one plain launch, one block per batch,
    // zero inter-block synchronization (batches are independent)
    loop_kernel<<<64, 512, 0, stream>>>(img, fpb, Wh, ab, va, Wcat, gemb, hseq, alph);

    // predictions = hseq @ W_out.T + b_out : [1984,32000] -> f32 (XCD-swizzled)
    gemm64_kernel<1, 1><<<dim3(500, 31), 256, 0, stream>>>(hseq, Woutb, 512, 512, 512, dout, 32000, bout);
}